// Round 4
// baseline (242.149 us; speedup 1.0000x reference)
//
#include <hip/hip_runtime.h>
#include <hip/hip_bf16.h>

// SelfTensorProductS2Grid via bf16 MFMA (16x16x32), register-resident, no LDS:
//   grid[g,c] = sum_i Wt[g,i] X[i,c];  out[i,c] = sum_g Wf[g,i] grid[g,c]^2
// g relabeled so stage-1 C/D layout IS stage-2 B-operand layout (baked into
// WfF prep). R3: 2 samples per wave (amortize W loads 2x), packed
// v_cvt_pk_bf16_f32 conversions, nontemporal output stores.

#define NN    4096
#define L2D   49
#define CCH   128
#define GTOT  324
#define MT1P  22              // stage-1 g-tiles of 16 (21 real + 1 zero pad)
#define KC2   11              // stage-2 g-chunks of 32

typedef __attribute__((ext_vector_type(8))) short bf16x8;
typedef __attribute__((ext_vector_type(4))) float f32x4;

#define WT_SHORTS (MT1P * 2 * 64 * 8)   // 22528
#define WF_SHORTS (4 * KC2 * 64 * 8)    // 22528

__device__ __forceinline__ short f2bf(float f) {
    union { float f; unsigned u; } x; x.f = f;
    return (short)((x.u + 0x7fffu + ((x.u >> 16) & 1u)) >> 16);   // RNE
}

__device__ __forceinline__ unsigned pack2bf(float a, float b) {
    // v_cvt_pk_bf16_f32 on gfx950; low 16 = a, high 16 = b
    __hip_bfloat162 p = __float22bfloat162_rn(make_float2(a, b));
    union { __hip_bfloat162 h; unsigned u; } c; c.h = p;
    return c.u;
}

// WtF[mt][kcx][lane][j]: A[m=g=mt*16+(lane&15)][k=i=kcx*32+(lane>>4)*8+j]
// WfF[it][kc2][lane][j]: A[m=i=it*16+(lane&15)][k=glog], where
//   gphys(glog) = kc2*32 + (j>>2)*16 + (lane>>4)*4 + (j&3)   <-- the relabel
__global__ void prep_w_kernel(const float* __restrict__ Wt,
                              const float* __restrict__ Wf,
                              short* __restrict__ WtF,
                              short* __restrict__ WfF)
{
    int idx = blockIdx.x * 256 + threadIdx.x;
    if (idx < WT_SHORTS) {
        int j = idx & 7, lane = (idx >> 3) & 63, kcx = (idx >> 9) & 1, mt = idx >> 10;
        int g = mt * 16 + (lane & 15);
        int i = kcx * 32 + (lane >> 4) * 8 + j;
        WtF[idx] = f2bf((g < GTOT && i < L2D) ? Wt[g * L2D + i] : 0.0f);
    } else if (idx < WT_SHORTS + WF_SHORTS) {
        int e = idx - WT_SHORTS;
        int j = e & 7, lane = (e >> 3) & 63, t = e >> 9;
        int kc2 = t % KC2, it = t / KC2;
        int i = it * 16 + (lane & 15);
        int g = kc2 * 32 + (j >> 2) * 16 + (lane >> 4) * 4 + (j & 3);
        WfF[e] = f2bf((g < GTOT && i < L2D) ? Wf[g * L2D + i] : 0.0f);
    }
}

__global__ __launch_bounds__(256, 2)
void stp_mfma3_kernel(const float* __restrict__ inp,
                      const short* __restrict__ WtF,
                      const short* __restrict__ WfF,
                      float* __restrict__ out)
{
    const int tid  = threadIdx.x;
    const int lane = tid & 63;
    const int wave = tid >> 6;
    const int lm   = lane & 15;
    const int quad = lane >> 4;

    const int task = blockIdx.x * 4 + wave;   // 4096 tasks = (n-pair, c-half)
    const int np   = task >> 1;
    const int h    = task & 1;
    const int n0   = np * 2;

    // ---- X B-fragments for both samples: B[k=i][n=c], packed cvt ----
    bf16x8 Bx[2][4][2];
    #pragma unroll
    for (int nn = 0; nn < 2; ++nn) {
        const float* __restrict__ Xn = inp + (size_t)(n0 + nn) * (L2D * CCH);
        #pragma unroll
        for (int t = 0; t < 4; ++t) {
            const int c = h * 64 + t * 16 + lm;
            #pragma unroll
            for (int kcx = 0; kcx < 2; ++kcx) {
                union { bf16x8 v; unsigned u[4]; } pk;
                #pragma unroll
                for (int d = 0; d < 4; ++d) {
                    const int i0 = kcx * 32 + quad * 8 + 2 * d;
                    float a = (i0     < L2D) ? Xn[(i0    ) * CCH + c] : 0.0f;
                    float b = (i0 + 1 < L2D) ? Xn[(i0 + 1) * CCH + c] : 0.0f;
                    pk.u[d] = pack2bf(a, b);
                }
                Bx[nn][t][kcx] = pk.v;
            }
        }
    }

    f32x4 acc2[2][4][4];   // [nn][it][t]
    #pragma unroll
    for (int nn = 0; nn < 2; ++nn)
        #pragma unroll
        for (int it = 0; it < 4; ++it)
            #pragma unroll
            for (int t = 0; t < 4; ++t)
                acc2[nn][it][t] = (f32x4){0.0f, 0.0f, 0.0f, 0.0f};

    #pragma unroll 1
    for (int kc2 = 0; kc2 < KC2; ++kc2) {
        // W fragments for this g-chunk (16B coalesced, L2-resident)
        bf16x8 Wtf[2][2];
        #pragma unroll
        for (int tt = 0; tt < 2; ++tt)
            #pragma unroll
            for (int kcx = 0; kcx < 2; ++kcx)
                Wtf[tt][kcx] = *(const bf16x8*)&WtF[(((2 * kc2 + tt) * 2 + kcx) * 64 + lane) * 8];
        bf16x8 Wff[4];
        #pragma unroll
        for (int it = 0; it < 4; ++it)
            Wff[it] = *(const bf16x8*)&WfF[((it * KC2 + kc2) * 64 + lane) * 8];

        #pragma unroll
        for (int nn = 0; nn < 2; ++nn) {
            #pragma unroll
            for (int t = 0; t < 4; ++t) {
                // stage 1: two 16-row g-tiles -> squared, packed into B-frag
                union { bf16x8 v; unsigned u[4]; } bg;
                #pragma unroll
                for (int tt = 0; tt < 2; ++tt) {
                    f32x4 g = (f32x4){0.0f, 0.0f, 0.0f, 0.0f};
                    g = __builtin_amdgcn_mfma_f32_16x16x32_bf16(Wtf[tt][0], Bx[nn][t][0], g, 0, 0, 0);
                    g = __builtin_amdgcn_mfma_f32_16x16x32_bf16(Wtf[tt][1], Bx[nn][t][1], g, 0, 0, 0);
                    bg.u[tt * 2 + 0] = pack2bf(g[0] * g[0], g[1] * g[1]);
                    bg.u[tt * 2 + 1] = pack2bf(g[2] * g[2], g[3] * g[3]);
                }
                // stage 2: accumulate out[i, c] over this g-chunk
                #pragma unroll
                for (int it = 0; it < 4; ++it)
                    acc2[nn][it][t] = __builtin_amdgcn_mfma_f32_16x16x32_bf16(Wff[it], bg.v, acc2[nn][it][t], 0, 0, 0);
            }
        }
    }

    // ---- store: C/D layout col=c=lm, row=i=it*16+quad*4+r; nontemporal ----
    #pragma unroll
    for (int nn = 0; nn < 2; ++nn) {
        float* __restrict__ On = out + (size_t)(n0 + nn) * (L2D * CCH);
        #pragma unroll
        for (int it = 0; it < 4; ++it) {
            #pragma unroll
            for (int t = 0; t < 4; ++t) {
                const int c = h * 64 + t * 16 + lm;
                #pragma unroll
                for (int r = 0; r < 4; ++r) {
                    const int i = it * 16 + quad * 4 + r;
                    if (i < L2D) __builtin_nontemporal_store(acc2[nn][it][t][r], &On[i * CCH + c]);
                }
            }
        }
    }
}

extern "C" void kernel_launch(void* const* d_in, const int* in_sizes, int n_in,
                              void* d_out, int out_size, void* d_ws, size_t ws_size,
                              hipStream_t stream) {
    const float* inp = (const float*)d_in[0];   // (4096, 49, 128) fp32
    const float* Wt  = (const float*)d_in[1];   // (18*18, 49) fp32
    const float* Wf  = (const float*)d_in[2];   // (18*18, 49) fp32
    float* out = (float*)d_out;                 // (4096, 49, 128) fp32

    short* WtF = (short*)d_ws;
    short* WfF = WtF + WT_SHORTS;               // total 90112 B of ws

    const int prep_threads = WT_SHORTS + WF_SHORTS;   // 45056
    prep_w_kernel<<<(prep_threads + 255) / 256, 256, 0, stream>>>(Wt, Wf, WtF, WfF);
    stp_mfma3_kernel<<<1024, 256, 0, stream>>>(inp, WtF, WfF, out);
}

// Round 5
// 231.554 us; speedup vs baseline: 1.0458x; 1.0458x over previous
//
#include <hip/hip_runtime.h>
#include <hip/hip_bf16.h>

// SelfTensorProductS2Grid via bf16 MFMA (16x16x32):
//   grid[g,c] = sum_i Wt[g,i] X[i,c];  out[i,c] = sum_g Wf[g,i] grid[g,c]^2
// g relabeled so stage-1 C/D layout IS stage-2 B-operand layout (baked into
// WfF prep). R4: one wave per (n, c-half) task as in R2 (best round), but the
// 4 waves of a block cooperatively double-buffer each kc2's 8 W fragments
// (8 KB) into LDS via global_load_lds(16B) -> W L2 traffic /4, in-loop load
// latency off the critical path. Packed v_cvt_pk_bf16_f32; nontemporal stores.

#define NN    4096
#define L2D   49
#define CCH   128
#define GTOT  324
#define MT1P  22              // stage-1 g-tiles of 16 (21 real + 1 zero pad)
#define KC2   11              // stage-2 g-chunks of 32
#define FRAG_SHORTS 512       // one fragment: 64 lanes x 8 bf16 = 1024 B

typedef __attribute__((ext_vector_type(8))) short bf16x8;
typedef __attribute__((ext_vector_type(4))) float f32x4;

#define WT_SHORTS (MT1P * 2 * 64 * 8)   // 22528
#define WF_SHORTS (4 * KC2 * 64 * 8)    // 22528

__device__ __forceinline__ short f2bf(float f) {
    union { float f; unsigned u; } x; x.f = f;
    return (short)((x.u + 0x7fffu + ((x.u >> 16) & 1u)) >> 16);   // RNE
}

__device__ __forceinline__ unsigned pack2bf(float a, float b) {
    __hip_bfloat162 p = __float22bfloat162_rn(make_float2(a, b));  // v_cvt_pk_bf16_f32
    union { __hip_bfloat162 h; unsigned u; } c; c.h = p;
    return c.u;
}

// WtF[mt][kcx][lane][j]: A[m=g=mt*16+(lane&15)][k=i=kcx*32+(lane>>4)*8+j]
// WfF[it][kc2][lane][j]: A[m=i=it*16+(lane&15)][k=glog], where
//   gphys(glog) = kc2*32 + (j>>2)*16 + (lane>>4)*4 + (j&3)   <-- the relabel
__global__ void prep_w_kernel(const float* __restrict__ Wt,
                              const float* __restrict__ Wf,
                              short* __restrict__ WtF,
                              short* __restrict__ WfF)
{
    int idx = blockIdx.x * 256 + threadIdx.x;
    if (idx < WT_SHORTS) {
        int j = idx & 7, lane = (idx >> 3) & 63, kcx = (idx >> 9) & 1, mt = idx >> 10;
        int g = mt * 16 + (lane & 15);
        int i = kcx * 32 + (lane >> 4) * 8 + j;
        WtF[idx] = f2bf((g < GTOT && i < L2D) ? Wt[g * L2D + i] : 0.0f);
    } else if (idx < WT_SHORTS + WF_SHORTS) {
        int e = idx - WT_SHORTS;
        int j = e & 7, lane = (e >> 3) & 63, t = e >> 9;
        int kc2 = t % KC2, it = t / KC2;
        int i = it * 16 + (lane & 15);
        int g = kc2 * 32 + (j >> 2) * 16 + (lane >> 4) * 4 + (j & 3);
        WfF[e] = f2bf((g < GTOT && i < L2D) ? Wf[g * L2D + i] : 0.0f);
    }
}

__global__ __launch_bounds__(256, 3)
void stp_mfma4_kernel(const float* __restrict__ inp,
                      const short* __restrict__ WtF,
                      const short* __restrict__ WfF,
                      float* __restrict__ out)
{
    // double-buffered W slab: 8 fragments per kc2 (4 Wt + 4 Wf) = 8 KB/buf
    __shared__ __align__(16) short Wbuf[2][8 * FRAG_SHORTS];   // 16 KB

    const int tid  = threadIdx.x;
    const int lane = tid & 63;
    const int wave = tid >> 6;
    const int lm   = lane & 15;
    const int quad = lane >> 4;

    const int h = blockIdx.x & 1;                 // c-half (shared by block)
    const int n = (blockIdx.x >> 1) * 4 + wave;   // sample for this wave

    const float* __restrict__ Xn = inp + (size_t)n * (L2D * CCH);

    // ---- stage kc2=0's fragments (wave w stages frags 2w, 2w+1) ----
    #define STAGE(buf, kc)                                                          \
        {                                                                           \
            _Pragma("unroll")                                                       \
            for (int p = 0; p < 2; ++p) {                                           \
                const int f = wave * 2 + p;                                         \
                const short* src = (f < 4)                                          \
                    ? (WtF + ((2 * (kc) + (f >> 1)) * 2 + (f & 1)) * FRAG_SHORTS)   \
                    : (WfF + ((f - 4) * KC2 + (kc)) * FRAG_SHORTS);                 \
                __builtin_amdgcn_global_load_lds(                                   \
                    (const __attribute__((address_space(1))) void*)(src + lane * 8),\
                    (__attribute__((address_space(3))) void*)(&Wbuf[(buf)][f * FRAG_SHORTS]), \
                    16, 0, 0);                                                      \
            }                                                                       \
        }

    STAGE(0, 0);

    // ---- X B-fragments: B[k=i][n=c], packed cvt (overlaps staging) ----
    bf16x8 Bx[4][2];
    #pragma unroll
    for (int t = 0; t < 4; ++t) {
        const int c = h * 64 + t * 16 + lm;
        #pragma unroll
        for (int kcx = 0; kcx < 2; ++kcx) {
            union { bf16x8 v; unsigned u[4]; } pk;
            #pragma unroll
            for (int d = 0; d < 4; ++d) {
                const int i0 = kcx * 32 + quad * 8 + 2 * d;
                float a = (i0     < L2D) ? Xn[(i0    ) * CCH + c] : 0.0f;
                float b = (i0 + 1 < L2D) ? Xn[(i0 + 1) * CCH + c] : 0.0f;
                pk.u[d] = pack2bf(a, b);
            }
            Bx[t][kcx] = pk.v;
        }
    }

    f32x4 acc2[4][4];   // [it][t]
    #pragma unroll
    for (int it = 0; it < 4; ++it)
        #pragma unroll
        for (int t = 0; t < 4; ++t)
            acc2[it][t] = (f32x4){0.0f, 0.0f, 0.0f, 0.0f};

    __syncthreads();    // buf0 staged (each wave drains its own vmcnt at barrier)

    int b = 0;
    #pragma unroll 1
    for (int kc2 = 0; kc2 < KC2; ++kc2) {
        if (kc2 + 1 < KC2) STAGE(b ^ 1, kc2 + 1);   // prefetch next slab

        const short* __restrict__ Wb = &Wbuf[b][0];
        bf16x8 Wtf[2][2];
        #pragma unroll
        for (int tt = 0; tt < 2; ++tt)
            #pragma unroll
            for (int kcx = 0; kcx < 2; ++kcx)
                Wtf[tt][kcx] = *(const bf16x8*)&Wb[(tt * 2 + kcx) * FRAG_SHORTS + lane * 8];
        bf16x8 Wff[4];
        #pragma unroll
        for (int it = 0; it < 4; ++it)
            Wff[it] = *(const bf16x8*)&Wb[(4 + it) * FRAG_SHORTS + lane * 8];

        #pragma unroll
        for (int t = 0; t < 4; ++t) {
            // stage 1: two 16-row g-tiles -> squared, packed into B-frag order
            union { bf16x8 v; unsigned u[4]; } bg;
            #pragma unroll
            for (int tt = 0; tt < 2; ++tt) {
                f32x4 g = (f32x4){0.0f, 0.0f, 0.0f, 0.0f};
                g = __builtin_amdgcn_mfma_f32_16x16x32_bf16(Wtf[tt][0], Bx[t][0], g, 0, 0, 0);
                g = __builtin_amdgcn_mfma_f32_16x16x32_bf16(Wtf[tt][1], Bx[t][1], g, 0, 0, 0);
                bg.u[tt * 2 + 0] = pack2bf(g[0] * g[0], g[1] * g[1]);
                bg.u[tt * 2 + 1] = pack2bf(g[2] * g[2], g[3] * g[3]);
            }
            // stage 2: accumulate out[i, c] over this g-chunk
            #pragma unroll
            for (int it = 0; it < 4; ++it)
                acc2[it][t] = __builtin_amdgcn_mfma_f32_16x16x32_bf16(Wff[it], bg.v, acc2[it][t], 0, 0, 0);
        }
        __syncthreads();   // ds_reads of buf b done; next slab (b^1) landed
        b ^= 1;
    }

    // ---- store: C/D layout col=c=lm, row=i=it*16+quad*4+r; nontemporal ----
    float* __restrict__ On = out + (size_t)n * (L2D * CCH);
    #pragma unroll
    for (int it = 0; it < 4; ++it) {
        #pragma unroll
        for (int t = 0; t < 4; ++t) {
            const int c = h * 64 + t * 16 + lm;
            #pragma unroll
            for (int r = 0; r < 4; ++r) {
                const int i = it * 16 + quad * 4 + r;
                if (i < L2D) __builtin_nontemporal_store(acc2[it][t][r], &On[i * CCH + c]);
            }
        }
    }
}

extern "C" void kernel_launch(void* const* d_in, const int* in_sizes, int n_in,
                              void* d_out, int out_size, void* d_ws, size_t ws_size,
                              hipStream_t stream) {
    const float* inp = (const float*)d_in[0];   // (4096, 49, 128) fp32
    const float* Wt  = (const float*)d_in[1];   // (18*18, 49) fp32
    const float* Wf  = (const float*)d_in[2];   // (18*18, 49) fp32
    float* out = (float*)d_out;                 // (4096, 49, 128) fp32

    short* WtF = (short*)d_ws;
    short* WfF = WtF + WT_SHORTS;               // total 90112 B of ws

    const int prep_threads = WT_SHORTS + WF_SHORTS;   // 45056
    prep_w_kernel<<<(prep_threads + 255) / 256, 256, 0, stream>>>(Wt, Wf, WtF, WfF);
    // 2048 blocks = 512 n-quads x 2 c-halves; 4 waves/block = 4 samples
    stp_mfma4_kernel<<<2048, 256, 0, stream>>>(inp, WtF, WfF, out);
}